// Round 2
// baseline (647.263 us; speedup 1.0000x reference)
//
#include <hip/hip_runtime.h>

#define EPSILON 0.001f
#define NSUP 601
#define ROWS_PER_BLOCK 64                        // 64*601 = 38464 floats: region size
#define FLOATS_PER_BLOCK (ROWS_PER_BLOCK * NSUP) //   and region START are both %4==0
#define F4_PER_BLOCK (FLOATS_PER_BLOCK / 4)      // 9616 float4 per block
#define BLOCK_THREADS 256

// ---------------------------------------------------------------------------
// Fused zero + two-hot scatter. Each block owns 64 contiguous rows (150.25 KB):
//   phase 1: coalesced float4 zero-fill of the region
//   phase 2 (after __syncthreads, which fences block-scope global stores):
//            threads 0..63 write the two probabilities for their row.
// The scatter lands on lines the block just wrote -> L2 hit, no HBM RMW fetch.
// Net HBM traffic = exactly one write of the 630 MB output.
// Program order within the scatter thread (lower then upper) reproduces the
// reference's "upper overwrites lower on index collision" semantics.
// ---------------------------------------------------------------------------
__global__ __launch_bounds__(BLOCK_THREADS)
void fused_twohot_kernel(const float* __restrict__ x,
                         const float* __restrict__ supports,
                         float* __restrict__ out) {
    const long long base = (long long)blockIdx.x * FLOATS_PER_BLOCK;
    float4* out4 = (float4*)(out + base);

    const float4 z = make_float4(0.f, 0.f, 0.f, 0.f);
    for (int j = threadIdx.x; j < F4_PER_BLOCK; j += BLOCK_THREADS) {
        out4[j] = z;
    }

    __syncthreads();   // block-scope barrier + global-memory fence

    if (threadIdx.x < ROWS_PER_BLOCK) {
        const int row = blockIdx.x * ROWS_PER_BLOCK + threadIdx.x;
        const float v = x[row];
        const float s = (v > 0.f) ? 1.f : ((v < 0.f) ? -1.f : 0.f);
        const float t = s * (sqrtf(fabsf(v) + 1.f) - 1.f + EPSILON * v);

        // supports = linspace(-300,300,601), unit spacing:
        // searchsorted(right)-1 == floor(t)+300, clamped.
        int idx = (int)floorf(t) + 300;
        const int lower = idx < 0 ? 0 : (idx > NSUP - 1 ? NSUP - 1 : idx);
        const int upper = (lower + 1 > NSUP - 1) ? NSUP - 1 : lower + 1;

        const float ls = supports[lower];
        const float us = supports[upper];
        const float p_low = (us - t) / (us - ls);   // denom == 1.0 in-range
        const float p_high = 1.f - p_low;

        float* rp = out + (long long)row * NSUP;
        rp[lower] = p_low;    // upper write wins on collision (clamp at top)
        rp[upper] = p_high;
    }
}

extern "C" void kernel_launch(void* const* d_in, const int* in_sizes, int n_in,
                              void* d_out, int out_size, void* d_ws, size_t ws_size,
                              hipStream_t stream) {
    const float* tv = (const float*)d_in[0];
    const float* supports = (const float*)d_in[1];
    float* out = (float*)d_out;

    const int nrows = in_sizes[0];                        // 4096*64 = 262144
    const int nblocks = nrows / ROWS_PER_BLOCK;           // 4096 blocks
    fused_twohot_kernel<<<nblocks, BLOCK_THREADS, 0, stream>>>(tv, supports, out);
}

// Round 3
// 641.595 us; speedup vs baseline: 1.0088x; 1.0088x over previous
//
#include <hip/hip_runtime.h>

#define EPSILON 0.001f
#define NSUP 601
#define WAVES_PER_BLOCK 4
#define BLOCK_THREADS (WAVES_PER_BLOCK * 64)

// ---------------------------------------------------------------------------
// One wave (64 lanes) per output row of 601 floats. The two-hot values are
// merged directly into the fill stream: lane writes p_low/p_high/0 depending
// on its column index. This writes the 630 MB output exactly once, with no
// read-modify-write, no barriers, and no separate scatter pass.
//
//   - t, lower, upper, p_low, p_high are wave-uniform (one row per wave);
//     x[row] is a same-address broadcast load, supports[] is L1-resident.
//   - dword stores: 64 lanes x 4 B = 256 B/instr, fully coalesced. Store
//     issue needs only ~10 B/cyc/CU to saturate HBM, so dword width is ample
//     and row-start misalignment (601 % 4 != 0) costs nothing.
//   - collision semantics: the reference writes p_low then p_high, so on the
//     top-clamp collision (lower==upper==600) p_high wins. Here the upper
//     check is applied after the lower check -> same result.
// ---------------------------------------------------------------------------
__global__ __launch_bounds__(BLOCK_THREADS)
void twohot_row_kernel(const float* __restrict__ x,
                       const float* __restrict__ supports,
                       float* __restrict__ out, int nrows) {
    const int wave = threadIdx.x >> 6;
    const int lane = threadIdx.x & 63;
    const int row = blockIdx.x * WAVES_PER_BLOCK + wave;
    if (row >= nrows) return;

    const float v = x[row];
    const float s = (v > 0.f) ? 1.f : ((v < 0.f) ? -1.f : 0.f);
    const float t = s * (sqrtf(fabsf(v) + 1.f) - 1.f + EPSILON * v);

    // supports = linspace(-300,300,601), unit spacing:
    // searchsorted(right)-1 == floor(t)+300, clamped.
    int idx = (int)floorf(t) + 300;
    const int lower = idx < 0 ? 0 : (idx > NSUP - 1 ? NSUP - 1 : idx);
    const int upper = (lower + 1 > NSUP - 1) ? NSUP - 1 : lower + 1;

    const float ls = supports[lower];
    const float us = supports[upper];
    const float p_low = (us - t) / (us - ls);   // denom == 1.0 in-range
    const float p_high = 1.f - p_low;

    float* rp = out + (long long)row * NSUP;
    #pragma unroll
    for (int it = 0; it < (NSUP + 63) / 64; ++it) {
        const int j = it * 64 + lane;
        if (j < NSUP) {
            float val = 0.f;
            if (j == lower) val = p_low;
            if (j == upper) val = p_high;   // applied last -> wins on collision
            rp[j] = val;
        }
    }
}

extern "C" void kernel_launch(void* const* d_in, const int* in_sizes, int n_in,
                              void* d_out, int out_size, void* d_ws, size_t ws_size,
                              hipStream_t stream) {
    const float* tv = (const float*)d_in[0];
    const float* supports = (const float*)d_in[1];
    float* out = (float*)d_out;

    const int nrows = in_sizes[0];   // 4096*64 = 262144
    const int nblocks = (nrows + WAVES_PER_BLOCK - 1) / WAVES_PER_BLOCK;  // 65536
    twohot_row_kernel<<<nblocks, BLOCK_THREADS, 0, stream>>>(tv, supports, out, nrows);
}

// Round 4
// 633.671 us; speedup vs baseline: 1.0214x; 1.0125x over previous
//
#include <hip/hip_runtime.h>

#define EPSILON 0.001f
#define NSUP 601
#define BLOCK_THREADS 256
#define NBLOCKS 4096                 // 16384 waves; 262144 rows -> 16 rows/wave

// ---------------------------------------------------------------------------
// One wave per output row, grid-striding over rows. Two-hot values are merged
// into the fill stream (no zero pass, no RMW, no barriers). vs round 3:
//   - persistent-style grid (4096 wg instead of 65536): removes any command-
//     processor dispatch-rate limit (9.6 KB/wg was ~1.5 ns/wg at 6.2 TB/s).
//   - float4 stores with head/tail alignment: 5 VMEM/row instead of 10.
//     Row start misalign is cyclic: (row*601)%4 == row%4, so head dwords
//     = (4 - row%4) & 3, then 149-150 aligned float4, then <=3 tail dwords.
//   - t, lower, upper, p_low, p_high wave-uniform; x[row] broadcast load;
//     supports[] L1-resident.
//   - collision semantics: upper test is taken first in the select chain, so
//     at the top clamp (lower==upper==600) p_high wins, matching the
//     reference's "upper overwrites lower" scatter order.
// ---------------------------------------------------------------------------
__global__ __launch_bounds__(BLOCK_THREADS)
void twohot_row_kernel(const float* __restrict__ x,
                       const float* __restrict__ supports,
                       float* __restrict__ out, int nrows, int nwaves_total) {
    const int wave = threadIdx.x >> 6;
    const int lane = threadIdx.x & 63;
    const int w0 = blockIdx.x * (BLOCK_THREADS / 64) + wave;

    for (int row = w0; row < nrows; row += nwaves_total) {
        const float v = x[row];
        const float s = (v > 0.f) ? 1.f : ((v < 0.f) ? -1.f : 0.f);
        const float t = s * (sqrtf(fabsf(v) + 1.f) - 1.f + EPSILON * v);

        // supports = linspace(-300,300,601), unit spacing:
        // searchsorted(right)-1 == floor(t)+300, clamped.
        int idx = (int)floorf(t) + 300;
        const int lower = idx < 0 ? 0 : (idx > NSUP - 1 ? NSUP - 1 : idx);
        const int upper = (lower + 1 > NSUP - 1) ? NSUP - 1 : lower + 1;

        const float ls = supports[lower];
        const float us = supports[upper];
        const float p_low = (us - t) / (us - ls);   // denom == 1.0 in-range
        const float p_high = 1.f - p_low;

        float* rp = out + (long long)row * NSUP;

        const int head = (4 - (row & 3)) & 3;       // dwords to 16B alignment
        const int nrem = NSUP - head;
        const int nf4 = nrem >> 2;                  // 149 or 150
        const int tail = nrem & 3;

        if (lane < head) {
            const int c = lane;
            rp[c] = (c == upper) ? p_high : ((c == lower) ? p_low : 0.f);
        }

        float4* rp4 = (float4*)(rp + head);         // 16B aligned by construction
        #pragma unroll
        for (int it = 0; it < 3; ++it) {
            const int f = it * 64 + lane;
            if (f < nf4) {
                const int c0 = head + f * 4;
                float4 val;
                val.x = (c0     == upper) ? p_high : ((c0     == lower) ? p_low : 0.f);
                val.y = (c0 + 1 == upper) ? p_high : ((c0 + 1 == lower) ? p_low : 0.f);
                val.z = (c0 + 2 == upper) ? p_high : ((c0 + 2 == lower) ? p_low : 0.f);
                val.w = (c0 + 3 == upper) ? p_high : ((c0 + 3 == lower) ? p_low : 0.f);
                rp4[f] = val;
            }
        }

        if (lane < tail) {
            const int c = head + nf4 * 4 + lane;
            rp[c] = (c == upper) ? p_high : ((c == lower) ? p_low : 0.f);
        }
    }
}

extern "C" void kernel_launch(void* const* d_in, const int* in_sizes, int n_in,
                              void* d_out, int out_size, void* d_ws, size_t ws_size,
                              hipStream_t stream) {
    const float* tv = (const float*)d_in[0];
    const float* supports = (const float*)d_in[1];
    float* out = (float*)d_out;

    const int nrows = in_sizes[0];                       // 4096*64 = 262144
    const int nwaves = NBLOCKS * (BLOCK_THREADS / 64);   // 16384
    twohot_row_kernel<<<NBLOCKS, BLOCK_THREADS, 0, stream>>>(
        tv, supports, out, nrows, nwaves);
}